// Round 7
// baseline (5073.417 us; speedup 1.0000x reference)
//
#include <hip/hip_runtime.h>
#include <hip/hip_fp16.h>
#include <math.h>

// Problem constants
#define NB 2048      // batch
#define ND 1024      // dim
#define EPS 0.05f
#define NITER 100
#define SBLK 256     // sinkhorn blocks (8 rows each; proven-fastest config)
#define KSCALE 16384.0f               // 2^14 — pulls f16 K into normal range
#define LOG_KSCALE 9.704060527839234  // log(2^14)

typedef float f32x4 __attribute__((ext_vector_type(4)));
typedef short s16x8 __attribute__((ext_vector_type(8)));
typedef unsigned short u16x4 __attribute__((ext_vector_type(4)));
union Uh { f32x4 f; __half2 h[4]; };

// ---------------- prep: w = nan_to_num(diag(L)), init u/v, zero counters+max ----------------
__global__ void prep_k(const float* __restrict__ L, float* __restrict__ w,
                       float* __restrict__ u, float* __restrict__ v,
                       unsigned* __restrict__ maxbits, unsigned* __restrict__ barr) {
    int gtid = blockIdx.x * 256 + threadIdx.x;   // 0..2047
    if (gtid < ND) {
        float x = L[(size_t)gtid * (ND + 1)];
        if (x != x) x = 0.f;
        else if (fabsf(x) == INFINITY) x = (x > 0.f) ? 3.4028235e38f : -3.4028235e38f;
        w[gtid] = x;
    }
    u[gtid] = 1.0f / NB;
    v[gtid] = 1.0f / NB;
    if (gtid == 0) *maxbits = 0u;
    if (gtid < 512) barr[gtid] = 0u;
}

// ---------------- per-row weighted squared norms ----------------
__global__ __launch_bounds__(256) void rows_k(const float* __restrict__ audio,
                                              const float* __restrict__ text,
                                              const float* __restrict__ w,
                                              float* __restrict__ aw, float* __restrict__ tw) {
    int r = blockIdx.x, tid = threadIdx.x;
    float4 wv = *(const float4*)&w[tid * 4];
    float4 a4 = *(const float4*)&audio[(size_t)r * ND + tid * 4];
    float4 t4 = *(const float4*)&text[(size_t)r * ND + tid * 4];
    float sa = a4.x * a4.x * wv.x + a4.y * a4.y * wv.y + a4.z * a4.z * wv.z + a4.w * a4.w * wv.w;
    float st = t4.x * t4.x * wv.x + t4.y * t4.y * wv.y + t4.z * t4.z * wv.z + t4.w * t4.w * wv.w;
    #pragma unroll
    for (int off = 32; off; off >>= 1) {
        sa += __shfl_down(sa, off, 64);
        st += __shfl_down(st, off, 64);
    }
    __shared__ float red[8];
    if ((tid & 63) == 0) { red[tid >> 6] = sa; red[4 + (tid >> 6)] = st; }
    __syncthreads();
    if (tid == 0) {
        aw[r] = red[0] + red[1] + red[2] + red[3];
        tw[r] = red[4] + red[5] + red[6] + red[7];
    }
}

// ---------------- f32 -> bf16 round-to-nearest-even (bit trick) ----------------
__device__ __forceinline__ unsigned short f2bf(float x) {
    unsigned uu = __float_as_uint(x);
    return (unsigned short)((uu + 0x7FFFu + ((uu >> 16) & 1u)) >> 16);
}

// ---------------- bf16 MFMA GEMM -> M_dist (f16, row + col major) + global max ----------------
__global__ __launch_bounds__(256) void gemm_mdist(
        const float* __restrict__ Tm, const float* __restrict__ Am,
        const float* __restrict__ wd, const float* __restrict__ tw, const float* __restrict__ aw,
        __half* __restrict__ Md, __half* __restrict__ MdT,
        float* __restrict__ diagMd, unsigned* __restrict__ maxbits) {
    __shared__ __align__(16) unsigned char smem[38912];
    float* wl = (float*)(smem + 34816);
    const int t = threadIdx.x;
    const int row0 = blockIdx.y * 128, col0 = blockIdx.x * 128;
    *(f32x4*)&wl[t * 4] = *(const f32x4*)&wd[t * 4];
    const int wv = t >> 6;                 // wave 0..3
    const int wr = wv >> 1, wc = wv & 1;   // 2x2 wave grid, 64x64 out each
    const int l = t & 63, lr = l & 15, kg = l >> 4;
    const int trow = t >> 4, tk4 = t & 15;
    const int px = (((tk4 >> 1) ^ (trow & 7)) << 4) + ((tk4 & 1) << 3);
    f32x4 acc[4][4];
    #pragma unroll
    for (int m = 0; m < 4; ++m)
        #pragma unroll
        for (int n = 0; n < 4; ++n) acc[m][n] = (f32x4){0.f, 0.f, 0.f, 0.f};
    __syncthreads();
    const float* tp = Tm + (size_t)(row0 + trow) * ND + tk4 * 4;
    const float* ap = Am + (size_t)(col0 + trow) * ND + tk4 * 4;
    for (int k0 = 0; k0 < ND; k0 += 64) {
        f32x4 wv4 = *(const f32x4*)&wl[k0 + tk4 * 4];
        __syncthreads();
        #pragma unroll
        for (int s = 0; s < 8; ++s) {
            f32x4 tv = *(const f32x4*)(tp + (size_t)(s * 16) * ND + k0);
            f32x4 av = *(const f32x4*)(ap + (size_t)(s * 16) * ND + k0);
            tv *= wv4;
            u16x4 tb, ab;
            tb[0] = f2bf(tv[0]); tb[1] = f2bf(tv[1]); tb[2] = f2bf(tv[2]); tb[3] = f2bf(tv[3]);
            ab[0] = f2bf(av[0]); ab[1] = f2bf(av[1]); ab[2] = f2bf(av[2]); ab[3] = f2bf(av[3]);
            const int rb = (s * 16 + trow) * 128 + px;
            *(u16x4*)(smem + rb) = tb;
            *(u16x4*)(smem + 16384 + rb) = ab;
        }
        __syncthreads();
        #pragma unroll
        for (int kk = 0; kk < 2; ++kk) {
            const int sl = (((kk << 2) + kg) ^ (lr & 7)) << 4;
            s16x8 af[4], bfr[4];
            #pragma unroll
            for (int m = 0; m < 4; ++m)
                af[m] = *(const s16x8*)(smem + (wr * 64 + m * 16 + lr) * 128 + sl);
            #pragma unroll
            for (int n = 0; n < 4; ++n)
                bfr[n] = *(const s16x8*)(smem + 16384 + (wc * 64 + n * 16 + lr) * 128 + sl);
            #pragma unroll
            for (int m = 0; m < 4; ++m)
                #pragma unroll
                for (int n = 0; n < 4; ++n)
                    acc[m][n] = __builtin_amdgcn_mfma_f32_16x16x32_bf16(af[m], bfr[n], acc[m][n], 0, 0, 0);
        }
    }
    __syncthreads();
    unsigned short* tr = (unsigned short*)smem;
    unsigned short* mdp = (unsigned short*)Md;
    float lmax = 0.f;
    #pragma unroll
    for (int m = 0; m < 4; ++m) {
        #pragma unroll
        for (int r = 0; r < 4; ++r) {
            const int li = wr * 64 + m * 16 + kg * 4 + r;
            const int i = row0 + li;
            const float twi = tw[i];
            #pragma unroll
            for (int n = 0; n < 4; ++n) {
                const int lj = wc * 64 + n * 16 + lr;
                const int j = col0 + lj;
                float md = twi + aw[j] - 2.0f * acc[m][n][r];
                md = sqrtf(fmaxf(md, 0.f));
                lmax = fmaxf(lmax, md);
                const unsigned short hb = __half_as_ushort(__float2half(md));
                mdp[(size_t)i * NB + j] = hb;
                tr[lj * 136 + li] = hb;
                if (i == j) diagMd[i] = md;
            }
        }
    }
    __syncthreads();
    {
        const int jj = t >> 1, ih = (t & 1) * 64;
        unsigned short* dst = (unsigned short*)MdT + (size_t)(col0 + jj) * NB + row0 + ih;
        #pragma unroll
        for (int x = 0; x < 8; ++x)
            *(s16x8*)(dst + x * 8) = *(const s16x8*)&tr[jj * 136 + ih + x * 8];
    }
    #pragma unroll
    for (int off = 32; off; off >>= 1) lmax = fmaxf(lmax, __shfl_down(lmax, off, 64));
    float* red = (float*)(smem + 34816);
    if (l == 0) red[t >> 6] = lmax;
    __syncthreads();
    if (t == 0) {
        float m2 = fmaxf(fmaxf(red[0], red[1]), fmaxf(red[2], red[3]));
        atomicMax(maxbits, __float_as_uint(m2));
    }
}

// ---------------- convert M_dist -> K' = exp(-md/(mx*eps)) * 2^14, in place (both majors) ----------------
__global__ __launch_bounds__(256) void expconv_k(__half* __restrict__ Kall,
                                                 const unsigned* __restrict__ maxbits) {
    const float mx = __uint_as_float(*maxbits);
    const float cc = -1.0f / (mx * EPS);
    size_t idx = ((size_t)blockIdx.x * 256 + threadIdx.x) << 3;   // 8 halfs per thread
    Uh uu; uu.f = *(const f32x4*)(Kall + idx);
    #pragma unroll
    for (int q = 0; q < 4; ++q) {
        float2 f = __half22float2(uu.h[q]);
        f.x = __expf(f.x * cc) * KSCALE;
        f.y = __expf(f.y * cc) * KSCALE;
        uu.h[q] = __floats2half2_rn(f.x, f.y);
    }
    *(f32x4*)(Kall + idx) = uu.f;
}

// ---------------- grid barrier (906-proven v1 original): ACQ_REL tree with resets ----------------
// barr: [0]=phase flag, [32]=root counter, [64+g*32]=group counters (g=0..7)
__device__ __forceinline__ void gsync(unsigned* barr, unsigned target) {
    __syncthreads();
    if (threadIdx.x == 0) {
        const int gg = blockIdx.x & 7;
        unsigned prev = __hip_atomic_fetch_add(&barr[64 + gg * 32], 1u,
                                               __ATOMIC_ACQ_REL, __HIP_MEMORY_SCOPE_AGENT);
        if (prev == (unsigned)(SBLK / 8) - 1u) {
            __hip_atomic_store(&barr[64 + gg * 32], 0u, __ATOMIC_RELAXED, __HIP_MEMORY_SCOPE_AGENT);
            unsigned rp = __hip_atomic_fetch_add(&barr[32], 1u,
                                                 __ATOMIC_ACQ_REL, __HIP_MEMORY_SCOPE_AGENT);
            if (rp == 7u) {
                __hip_atomic_store(&barr[32], 0u, __ATOMIC_RELAXED, __HIP_MEMORY_SCOPE_AGENT);
                __hip_atomic_store(&barr[0], target, __ATOMIC_RELEASE, __HIP_MEMORY_SCOPE_AGENT);
            }
        }
        while (__hip_atomic_load(&barr[0], __ATOMIC_ACQUIRE, __HIP_MEMORY_SCOPE_AGENT) < target)
            __builtin_amdgcn_s_sleep(2);
    }
    __syncthreads();
}

// ---------------- LLC-coherent 32B staged load into padded LDS ----------------
__device__ __forceinline__ void stage(const float* __restrict__ src, float* sv, int tid) {
    const float* p0 = src + (tid << 3);
    f32x4 r0, r1;
    asm volatile("global_load_dwordx4 %0, %2, off sc0 sc1\n\t"
                 "global_load_dwordx4 %1, %3, off sc0 sc1\n\t"
                 "s_waitcnt vmcnt(0)"
                 : "=&v"(r0), "=&v"(r1) : "v"(p0), "v"(p0 + 4) : "memory");
    // padded LDS layout: logical i -> i + (i/8)*4  (conflict-free b128 reads)
    *(f32x4*)&sv[tid * 12] = r0;
    *(f32x4*)&sv[tid * 12 + 4] = r1;
}

// ---------------- one half-step from LDS-resident K row: xout[row] = ab / (Krow . sv) ----------------
__device__ __forceinline__ void half_step_l(const __half* __restrict__ krow,
                                            float* __restrict__ xout,
                                            const float* sv, int row, float ab, int l) {
    float sum = 0.f;
    #pragma unroll
    for (int c8 = 0; c8 < 8; ++c8) {
        const int base = (c8 << 8) + (l << 3);         // 32 lanes x 8 halfs = 256 cols/chunk
        const int phys = base + ((base >> 3) << 2);    // padded sv index
        f32x4 s0 = *(const f32x4*)&sv[phys];
        f32x4 s1 = *(const f32x4*)&sv[phys + 4];
        Uh uu; uu.f = *(const f32x4*)(krow + base);    // ds_read_b128 (K in LDS)
        float2 f0 = __half22float2(uu.h[0]);
        float2 f1 = __half22float2(uu.h[1]);
        float2 f2 = __half22float2(uu.h[2]);
        float2 f3 = __half22float2(uu.h[3]);
        sum = fmaf(f0.x, s0.x, sum);
        sum = fmaf(f0.y, s0.y, sum);
        sum = fmaf(f1.x, s0.z, sum);
        sum = fmaf(f1.y, s0.w, sum);
        sum = fmaf(f2.x, s1.x, sum);
        sum = fmaf(f2.y, s1.y, sum);
        sum = fmaf(f3.x, s1.z, sum);
        sum = fmaf(f3.y, s1.w, sum);
    }
    #pragma unroll
    for (int off = 16; off; off >>= 1) sum += __shfl_down(sum, off, 32);
    if (l == 0)
        __hip_atomic_store(&xout[row], ab / sum, __ATOMIC_RELEASE, __HIP_MEMORY_SCOPE_AGENT);
}

// ---------------- persistent Sinkhorn: 100 x { v = b/(K^T u); u = a/(K v) } ----------------
// 256 blocks x 8 rows (one row per 32-lane group). K rows preloaded into LDS once:
// barrier L2-invalidates can no longer evict them.
__global__ __launch_bounds__(256, 1) void sinkhorn_k(
        const __half* __restrict__ Kr, const __half* __restrict__ Kc,
        float* __restrict__ u, float* __restrict__ v,
        unsigned* __restrict__ barr) {
    __shared__ __align__(16) __half Kl[2][8][2048];   // [0]=Kc rows (v-step), [1]=Kr rows: 64KB
    __shared__ __align__(16) float sv[3072];          // 2048 floats, padded (i + i/8*4)
    const int tid = threadIdx.x, bid = blockIdx.x;
    const int g = tid >> 5, l = tid & 31;
    const int row = (bid << 3) + g;                   // 8 rows/block
    const float ab = 1.0f / NB;
    // ---- one-time preload of this block's K' rows (8 x 4KB per matrix) ----
    {
        const __half* gc = Kc + (size_t)(bid << 3) * NB;
        const __half* gr = Kr + (size_t)(bid << 3) * NB;
        #pragma unroll
        for (int r8 = 0; r8 < 8; ++r8) {
            const int e = (r8 << 11) + (tid << 3);    // 256 thr x 8 halfs = one 2048-half row
            *(f32x4*)&Kl[0][0][e] = *(const f32x4*)(gc + e);
            *(f32x4*)&Kl[1][0][e] = *(const f32x4*)(gr + e);
        }
    }
    __syncthreads();
    unsigned phase = 0;
    for (int it = 0; it < NITER; ++it) {
        // ---- v-step: v = b / (K^T u) ----
        stage(u, sv, tid);
        __syncthreads();
        half_step_l(&Kl[0][g][0], v, sv, row, ab, l);
        gsync(barr, ++phase);
        // ---- u-step: u = a / (K v) ----
        stage(v, sv, tid);
        __syncthreads();
        half_step_l(&Kl[1][g][0], u, sv, row, ab, l);
        gsync(barr, ++phase);
    }
}

// ---------------- loss: -(1/B) * sum_i [log u_i + log v_i + log K_ii] - log(2^14) ----------------
__global__ void loss_k(const float* __restrict__ u, const float* __restrict__ v,
                       const float* __restrict__ diagMd, const unsigned* __restrict__ maxbits,
                       float* __restrict__ out) {
    int tid = threadIdx.x;
    float mx = __uint_as_float(*maxbits);
    float cc = 1.0f / (mx * EPS);
    double s = 0.0;
    for (int i = tid; i < NB; i += 256)
        s += (double)(logf(u[i]) + logf(v[i]) - diagMd[i] * cc);
    #pragma unroll
    for (int off = 32; off; off >>= 1) s += __shfl_down(s, off, 64);
    __shared__ double red[4];
    if ((tid & 63) == 0) red[tid >> 6] = s;
    __syncthreads();
    if (tid == 0)
        out[0] = (float)(-(red[0] + red[1] + red[2] + red[3]) / (double)NB - LOG_KSCALE);
}

// ---------------- launch ----------------
extern "C" void kernel_launch(void* const* d_in, const int* in_sizes, int n_in,
                              void* d_out, int out_size, void* d_ws, size_t ws_size,
                              hipStream_t stream) {
    const float* audio = (const float*)d_in[0];
    const float* text  = (const float*)d_in[1];
    const float* L     = (const float*)d_in[2];
    char* ws = (char*)d_ws;
    float*    w       = (float*)(ws + 0);
    float*    aw      = (float*)(ws + 4096);
    float*    tw      = (float*)(ws + 12288);
    float*    u       = (float*)(ws + 20480);
    float*    v       = (float*)(ws + 28672);
    float*    diagMd  = (float*)(ws + 36864);
    unsigned* maxbits = (unsigned*)(ws + 45056);
    unsigned* barr    = (unsigned*)(ws + 45312);
    __half*   Md      = (__half*)(ws + 65536);                          // becomes Kr
    __half*   MdT     = (__half*)(ws + 65536 + (size_t)NB * NB * 2);    // becomes Kc

    prep_k<<<8, 256, 0, stream>>>(L, w, u, v, maxbits, barr);
    rows_k<<<NB, 256, 0, stream>>>(audio, text, w, aw, tw);
    gemm_mdist<<<dim3(16, 16), 256, 0, stream>>>(text, audio, w, tw, aw, Md, MdT, diagMd, maxbits);
    expconv_k<<<4096, 256, 0, stream>>>(Md, maxbits);   // Md & MdT contiguous: 2*NB*NB halfs
    sinkhorn_k<<<SBLK, 256, 0, stream>>>(Md, MdT, u, v, barr);
    loss_k<<<1, 256, 0, stream>>>(u, v, diagMd, maxbits, (float*)d_out);
}

// Round 8
// 878.396 us; speedup vs baseline: 5.7758x; 5.7758x over previous
//
#include <hip/hip_runtime.h>
#include <hip/hip_fp16.h>
#include <math.h>

// Problem constants
#define NB 2048      // batch
#define ND 1024      // dim
#define EPS 0.05f
#define NITER 100
#define SBLK 64      // sinkhorn blocks x 512 threads; 32 rows/block
#define KSCALE 16384.0f               // 2^14 — pulls f16 K into normal range
#define LOG_KSCALE 9.704060527839234  // log(2^14)

typedef float f32x4 __attribute__((ext_vector_type(4)));
typedef short s16x8 __attribute__((ext_vector_type(8)));
typedef unsigned short u16x4 __attribute__((ext_vector_type(4)));
union Uh { f32x4 f; __half2 h[4]; };

// ---------------- prep: w = nan_to_num(diag(L)), init u/v, zero flags+max ----------------
__global__ void prep_k(const float* __restrict__ L, float* __restrict__ w,
                       float* __restrict__ u, float* __restrict__ v,
                       unsigned* __restrict__ maxbits, unsigned* __restrict__ flags) {
    int gtid = blockIdx.x * 256 + threadIdx.x;   // 0..2047
    if (gtid < ND) {
        float x = L[(size_t)gtid * (ND + 1)];
        if (x != x) x = 0.f;
        else if (fabsf(x) == INFINITY) x = (x > 0.f) ? 3.4028235e38f : -3.4028235e38f;
        w[gtid] = x;
    }
    u[gtid] = 1.0f / NB;
    v[gtid] = 1.0f / NB;
    if (gtid == 0) *maxbits = 0u;
    if (gtid < 512) flags[gtid] = 0u;
}

// ---------------- per-row weighted squared norms ----------------
__global__ __launch_bounds__(256) void rows_k(const float* __restrict__ audio,
                                              const float* __restrict__ text,
                                              const float* __restrict__ w,
                                              float* __restrict__ aw, float* __restrict__ tw) {
    int r = blockIdx.x, tid = threadIdx.x;
    float4 wv = *(const float4*)&w[tid * 4];
    float4 a4 = *(const float4*)&audio[(size_t)r * ND + tid * 4];
    float4 t4 = *(const float4*)&text[(size_t)r * ND + tid * 4];
    float sa = a4.x * a4.x * wv.x + a4.y * a4.y * wv.y + a4.z * a4.z * wv.z + a4.w * a4.w * wv.w;
    float st = t4.x * t4.x * wv.x + t4.y * t4.y * wv.y + t4.z * t4.z * wv.z + t4.w * t4.w * wv.w;
    #pragma unroll
    for (int off = 32; off; off >>= 1) {
        sa += __shfl_down(sa, off, 64);
        st += __shfl_down(st, off, 64);
    }
    __shared__ float red[8];
    if ((tid & 63) == 0) { red[tid >> 6] = sa; red[4 + (tid >> 6)] = st; }
    __syncthreads();
    if (tid == 0) {
        aw[r] = red[0] + red[1] + red[2] + red[3];
        tw[r] = red[4] + red[5] + red[6] + red[7];
    }
}

// ---------------- f32 -> bf16 round-to-nearest-even (bit trick) ----------------
__device__ __forceinline__ unsigned short f2bf(float x) {
    unsigned uu = __float_as_uint(x);
    return (unsigned short)((uu + 0x7FFFu + ((uu >> 16) & 1u)) >> 16);
}

// ---------------- bf16 MFMA GEMM -> M_dist (f16, row + col major) + global max ----------------
__global__ __launch_bounds__(256) void gemm_mdist(
        const float* __restrict__ Tm, const float* __restrict__ Am,
        const float* __restrict__ wd, const float* __restrict__ tw, const float* __restrict__ aw,
        __half* __restrict__ Md, __half* __restrict__ MdT,
        float* __restrict__ diagMd, unsigned* __restrict__ maxbits) {
    __shared__ __align__(16) unsigned char smem[38912];
    float* wl = (float*)(smem + 34816);
    const int t = threadIdx.x;
    const int row0 = blockIdx.y * 128, col0 = blockIdx.x * 128;
    *(f32x4*)&wl[t * 4] = *(const f32x4*)&wd[t * 4];
    const int wv = t >> 6;                 // wave 0..3
    const int wr = wv >> 1, wc = wv & 1;   // 2x2 wave grid, 64x64 out each
    const int l = t & 63, lr = l & 15, kg = l >> 4;
    const int trow = t >> 4, tk4 = t & 15;
    const int px = (((tk4 >> 1) ^ (trow & 7)) << 4) + ((tk4 & 1) << 3);
    f32x4 acc[4][4];
    #pragma unroll
    for (int m = 0; m < 4; ++m)
        #pragma unroll
        for (int n = 0; n < 4; ++n) acc[m][n] = (f32x4){0.f, 0.f, 0.f, 0.f};
    __syncthreads();
    const float* tp = Tm + (size_t)(row0 + trow) * ND + tk4 * 4;
    const float* ap = Am + (size_t)(col0 + trow) * ND + tk4 * 4;
    for (int k0 = 0; k0 < ND; k0 += 64) {
        f32x4 wv4 = *(const f32x4*)&wl[k0 + tk4 * 4];
        __syncthreads();
        #pragma unroll
        for (int s = 0; s < 8; ++s) {
            f32x4 tv = *(const f32x4*)(tp + (size_t)(s * 16) * ND + k0);
            f32x4 av = *(const f32x4*)(ap + (size_t)(s * 16) * ND + k0);
            tv *= wv4;
            u16x4 tb, ab;
            tb[0] = f2bf(tv[0]); tb[1] = f2bf(tv[1]); tb[2] = f2bf(tv[2]); tb[3] = f2bf(tv[3]);
            ab[0] = f2bf(av[0]); ab[1] = f2bf(av[1]); ab[2] = f2bf(av[2]); ab[3] = f2bf(av[3]);
            const int rb = (s * 16 + trow) * 128 + px;
            *(u16x4*)(smem + rb) = tb;
            *(u16x4*)(smem + 16384 + rb) = ab;
        }
        __syncthreads();
        #pragma unroll
        for (int kk = 0; kk < 2; ++kk) {
            const int sl = (((kk << 2) + kg) ^ (lr & 7)) << 4;
            s16x8 af[4], bfr[4];
            #pragma unroll
            for (int m = 0; m < 4; ++m)
                af[m] = *(const s16x8*)(smem + (wr * 64 + m * 16 + lr) * 128 + sl);
            #pragma unroll
            for (int n = 0; n < 4; ++n)
                bfr[n] = *(const s16x8*)(smem + 16384 + (wc * 64 + n * 16 + lr) * 128 + sl);
            #pragma unroll
            for (int m = 0; m < 4; ++m)
                #pragma unroll
                for (int n = 0; n < 4; ++n)
                    acc[m][n] = __builtin_amdgcn_mfma_f32_16x16x32_bf16(af[m], bfr[n], acc[m][n], 0, 0, 0);
        }
    }
    __syncthreads();
    unsigned short* tr = (unsigned short*)smem;
    unsigned short* mdp = (unsigned short*)Md;
    float lmax = 0.f;
    #pragma unroll
    for (int m = 0; m < 4; ++m) {
        #pragma unroll
        for (int r = 0; r < 4; ++r) {
            const int li = wr * 64 + m * 16 + kg * 4 + r;
            const int i = row0 + li;
            const float twi = tw[i];
            #pragma unroll
            for (int n = 0; n < 4; ++n) {
                const int lj = wc * 64 + n * 16 + lr;
                const int j = col0 + lj;
                float md = twi + aw[j] - 2.0f * acc[m][n][r];
                md = sqrtf(fmaxf(md, 0.f));
                lmax = fmaxf(lmax, md);
                const unsigned short hb = __half_as_ushort(__float2half(md));
                mdp[(size_t)i * NB + j] = hb;
                tr[lj * 136 + li] = hb;
                if (i == j) diagMd[i] = md;
            }
        }
    }
    __syncthreads();
    {
        const int jj = t >> 1, ih = (t & 1) * 64;
        unsigned short* dst = (unsigned short*)MdT + (size_t)(col0 + jj) * NB + row0 + ih;
        #pragma unroll
        for (int x = 0; x < 8; ++x)
            *(s16x8*)(dst + x * 8) = *(const s16x8*)&tr[jj * 136 + ih + x * 8];
    }
    #pragma unroll
    for (int off = 32; off; off >>= 1) lmax = fmaxf(lmax, __shfl_down(lmax, off, 64));
    float* red = (float*)(smem + 34816);
    if (l == 0) red[t >> 6] = lmax;
    __syncthreads();
    if (t == 0) {
        float m2 = fmaxf(fmaxf(red[0], red[1]), fmaxf(red[2], red[3]));
        atomicMax(maxbits, __float_as_uint(m2));
    }
}

// ---------------- convert M_dist -> K' = exp(-md/(mx*eps)) * 2^14, in place (both majors) ----------------
__global__ __launch_bounds__(256) void expconv_k(__half* __restrict__ Kall,
                                                 const unsigned* __restrict__ maxbits) {
    const float mx = __uint_as_float(*maxbits);
    const float cc = -1.0f / (mx * EPS);
    size_t idx = ((size_t)blockIdx.x * 256 + threadIdx.x) << 3;   // 8 halfs per thread
    Uh uu; uu.f = *(const f32x4*)(Kall + idx);
    #pragma unroll
    for (int q = 0; q < 4; ++q) {
        float2 f = __half22float2(uu.h[q]);
        f.x = __expf(f.x * cc) * KSCALE;
        f.y = __expf(f.y * cc) * KSCALE;
        uu.h[q] = __floats2half2_rn(f.x, f.y);
    }
    *(f32x4*)(Kall + idx) = uu.f;
}

// ---------------- store-broadcast barrier: 64 flags (16B apart), no RMW anywhere ----------------
// wave 0 polls: lane l loads flags[l*4]; all lanes' flags >= ph -> done.
__device__ __forceinline__ void wait_phase(const unsigned* __restrict__ pollp, int w, unsigned ph) {
    if (w == 0) {
        for (;;) {
            unsigned f;
            asm volatile("global_load_dword %0, %1, off sc0 sc1\n\t"
                         "s_waitcnt vmcnt(0)"
                         : "=&v"(f) : "v"(pollp) : "memory");
            if (__all(f >= ph)) break;
            __builtin_amdgcn_s_sleep(1);
        }
    }
}

// ---------------- LLC-coherent stage: 512 threads x 4 floats -> padded LDS ----------------
__device__ __forceinline__ void stage(const float* __restrict__ src, float* sv, int tid) {
    const float* p0 = src + (tid << 2);
    f32x4 r0;
    asm volatile("global_load_dwordx4 %0, %1, off sc0 sc1\n\t"
                 "s_waitcnt vmcnt(0)"
                 : "=&v"(r0) : "v"(p0) : "memory");
    // padded LDS layout: logical i -> i + (i/8)*4  (conflict-free b128 reads)
    *(f32x4*)&sv[(tid << 2) + ((tid >> 1) << 2)] = r0;
}

// ---------------- one half-step: xout[row0..3] = ab / (K[rows] . sv); lane0 16B store ----------------
__device__ __forceinline__ void half_step(const __half* __restrict__ Kmat,
                                          float* __restrict__ xout,
                                          const float* sv, int row0, float ab, int l) {
    float acc[4] = {0.f, 0.f, 0.f, 0.f};
    const __half* kb = Kmat + (size_t)row0 * NB;
    #pragma unroll
    for (int c = 0; c < 4; ++c) {
        const int col = (c << 9) + (l << 3);           // lane covers 4 chunks of 8 cols
        const int phys = col + ((col >> 3) << 2);      // padded LDS index
        f32x4 s0 = *(const f32x4*)&sv[phys];
        f32x4 s1 = *(const f32x4*)&sv[phys + 4];
        #pragma unroll
        for (int r = 0; r < 4; ++r) {
            Uh uu; uu.f = *(const f32x4*)(kb + (size_t)r * NB + col);   // plain cached loads (K read-only)
            float2 f0 = __half22float2(uu.h[0]);
            float2 f1 = __half22float2(uu.h[1]);
            float2 f2 = __half22float2(uu.h[2]);
            float2 f3 = __half22float2(uu.h[3]);
            acc[r] = fmaf(f0.x, s0.x, acc[r]);
            acc[r] = fmaf(f0.y, s0.y, acc[r]);
            acc[r] = fmaf(f1.x, s0.z, acc[r]);
            acc[r] = fmaf(f1.y, s0.w, acc[r]);
            acc[r] = fmaf(f2.x, s1.x, acc[r]);
            acc[r] = fmaf(f2.y, s1.y, acc[r]);
            acc[r] = fmaf(f3.x, s1.z, acc[r]);
            acc[r] = fmaf(f3.y, s1.w, acc[r]);
        }
    }
    #pragma unroll
    for (int r = 0; r < 4; ++r) {
        #pragma unroll
        for (int off = 32; off; off >>= 1) acc[r] += __shfl_down(acc[r], off, 64);
    }
    if (l == 0) {
        f32x4 o;
        o[0] = ab / acc[0]; o[1] = ab / acc[1]; o[2] = ab / acc[2]; o[3] = ab / acc[3];
        asm volatile("global_store_dwordx4 %1, %0, off sc0 sc1"
                     :: "v"(o), "v"(xout + row0) : "memory");
    }
    asm volatile("s_waitcnt vmcnt(0)" ::: "memory");   // wave-wide drain before the barrier
}

// ---------------- persistent Sinkhorn: 100 x { v = b/(K^T u); u = a/(K v) } ----------------
// 64 blocks x 8 waves x 4 rows. Arrivals are single stores to per-block flags
// (monotonic, no RMW, no acquire/release -> no L2 invalidates ever).
__global__ __launch_bounds__(512, 1) void sinkhorn_k(
        const __half* __restrict__ Kr, const __half* __restrict__ Kc,
        float* __restrict__ u, float* __restrict__ v,
        unsigned* __restrict__ flags) {
    __shared__ __align__(16) float sv[3072];   // 2048 floats, padded (i + i/8*4)
    const int tid = threadIdx.x, bid = blockIdx.x;
    const int w = tid >> 6, l = tid & 63;
    const int row0 = ((bid << 3) + w) << 2;    // 32 rows/block, 4 rows/wave
    const float ab = 1.0f / NB;
    unsigned* myflag = flags + (bid << 2);                 // 16B apart
    const unsigned* pollp = flags + ((l & 63) << 2);       // lane l -> block l's flag
    for (int it = 0; it < NITER; ++it) {
        // ---- v-step: v = b / (K^T u); needs u@it (phase 2it) ----
        wait_phase(pollp, w, 2 * it);
        __syncthreads();                       // release block; also fences prior sv reads
        stage(u, sv, tid);
        __syncthreads();
        half_step(Kc, v, sv, row0, ab, l);     // compute + store + wave drain
        __syncthreads();                       // all waves' stores drained
        if (tid == 0) {
            unsigned ph = 2 * it + 1;
            asm volatile("global_store_dword %1, %0, off sc0 sc1"
                         :: "v"(ph), "v"(myflag) : "memory");
        }
        // ---- u-step: u = a / (K v); needs v@it+1 (phase 2it+1) ----
        wait_phase(pollp, w, 2 * it + 1);
        __syncthreads();
        stage(v, sv, tid);
        __syncthreads();
        half_step(Kr, u, sv, row0, ab, l);
        __syncthreads();
        if (tid == 0) {
            unsigned ph = 2 * it + 2;
            asm volatile("global_store_dword %1, %0, off sc0 sc1"
                         :: "v"(ph), "v"(myflag) : "memory");
        }
    }
}

// ---------------- loss: -(1/B) * sum_i [log u_i + log v_i + log K_ii] - log(2^14) ----------------
__global__ void loss_k(const float* __restrict__ u, const float* __restrict__ v,
                       const float* __restrict__ diagMd, const unsigned* __restrict__ maxbits,
                       float* __restrict__ out) {
    int tid = threadIdx.x;
    float mx = __uint_as_float(*maxbits);
    float cc = 1.0f / (mx * EPS);
    double s = 0.0;
    for (int i = tid; i < NB; i += 256)
        s += (double)(logf(u[i]) + logf(v[i]) - diagMd[i] * cc);
    #pragma unroll
    for (int off = 32; off; off >>= 1) s += __shfl_down(s, off, 64);
    __shared__ double red[4];
    if ((tid & 63) == 0) red[tid >> 6] = s;
    __syncthreads();
    if (tid == 0)
        out[0] = (float)(-(red[0] + red[1] + red[2] + red[3]) / (double)NB - LOG_KSCALE);
}

// ---------------- launch ----------------
extern "C" void kernel_launch(void* const* d_in, const int* in_sizes, int n_in,
                              void* d_out, int out_size, void* d_ws, size_t ws_size,
                              hipStream_t stream) {
    const float* audio = (const float*)d_in[0];
    const float* text  = (const float*)d_in[1];
    const float* L     = (const float*)d_in[2];
    char* ws = (char*)d_ws;
    float*    w       = (float*)(ws + 0);
    float*    aw      = (float*)(ws + 4096);
    float*    tw      = (float*)(ws + 12288);
    float*    u       = (float*)(ws + 20480);
    float*    v       = (float*)(ws + 28672);
    float*    diagMd  = (float*)(ws + 36864);
    unsigned* maxbits = (unsigned*)(ws + 45056);
    unsigned* flags   = (unsigned*)(ws + 45312);
    __half*   Md      = (__half*)(ws + 65536);                          // becomes Kr
    __half*   MdT     = (__half*)(ws + 65536 + (size_t)NB * NB * 2);    // becomes Kc

    prep_k<<<8, 256, 0, stream>>>(L, w, u, v, maxbits, flags);
    rows_k<<<NB, 256, 0, stream>>>(audio, text, w, aw, tw);
    gemm_mdist<<<dim3(16, 16), 256, 0, stream>>>(text, audio, w, tw, aw, Md, MdT, diagMd, maxbits);
    expconv_k<<<4096, 256, 0, stream>>>(Md, maxbits);   // Md & MdT contiguous: 2*NB*NB halfs
    sinkhorn_k<<<SBLK, 512, 0, stream>>>(Md, MdT, u, v, flags);
    loss_k<<<1, 256, 0, stream>>>(u, v, diagMd, maxbits, (float*)d_out);
}